// Round 11
// baseline (41.685 us; speedup 1.0000x reference)
//
#include <hip/hip_runtime.h>
#include <hip/hip_bf16.h>

// out[b,o] = sum_{i,n} T_n(x[b,i]) * w[o,i,n]
// GEMM view: M=B=65536, N=O=32, K=I*8=2048. MFMA v_mfma_f32_32x32x16_bf16.
// Round-11: NO x staging. Each lane gathers its own row-slice of x directly
// into registers (float4 = 2 iterations' worth; lanes l and l+32 share the
// address -> HW broadcast). Depth-4 register pipelines on both x and B.
// Zero barriers / zero LDS until the partial-reduce epilogue (R4-proven).
// Kills the per-block stage->compute convoy that pinned rounds 2-10 at ~29+ us.
// Inner math byte-identical to round 10 (PASSED, absmax 1.95e-3).

typedef __attribute__((ext_vector_type(8)))  short bf16x8;
typedef __attribute__((ext_vector_type(16))) float f32x16;
typedef __attribute__((ext_vector_type(4)))  float f32x4;

__device__ __forceinline__ short f2b(float f) {     // RN (prep only)
    __hip_bfloat16 h = __float2bfloat16(f);
    short s;
    __builtin_memcpy(&s, &h, sizeof(s));
    return s;
}

// pack {hi16(hi), hi16(lo)} in ONE v_perm_b32 (truncating bf16 pack)
__device__ __forceinline__ unsigned pkbf_tr(float lo, float hi) {
    unsigned a, b;
    __builtin_memcpy(&a, &hi, 4);
    __builtin_memcpy(&b, &lo, 4);
    return __builtin_amdgcn_perm(a, b, 0x07060302u);
}

// Pack w [32][256][8] fp32 -> wB[kc2][lane][jj] bf16 in B-fragment order:
//   o = lane&31, g = lane>>5, i = 2*kc2 + (jj>>2), n = 4*g + (jj&3)
// (HW-verified: rounds 2-10 passed with this layout)
__global__ __launch_bounds__(256) void prep_w_kernel(const float* __restrict__ w,
                                                     short* __restrict__ wB) {
    int idx = blockIdx.x * 256 + threadIdx.x;     // 0..65535
    int kc2 = idx >> 9;
    int l   = (idx >> 3) & 63;
    int jj  = idx & 7;
    int o = l & 31, g = l >> 5;
    int i = 2 * kc2 + (jj >> 2);
    int n = 4 * g + (jj & 3);
    wB[idx] = f2b(w[(o * 256 + i) * 8 + n]);
}

__global__ __launch_bounds__(256, 5) void cheb_mm_kernel(const float* __restrict__ x,
                                                         const short* __restrict__ wB,
                                                         float* __restrict__ out) {
    __shared__ float smem[4096];                  // 16 KB: partials only
    const int tid = threadIdx.x;
    const int wv  = tid >> 6;                     // K-quarter selector
    const int l   = tid & 63;
    const int g   = l >> 5;                       // i-parity this lane computes
    const int r0  = l & 31;                       // batch row in tile / o column
    const long long rowB = (long long)blockIdx.x * 32;

    // lane's private x row-slice: float4 cc covers i-pairs {2cc, 2cc+1} of
    // this wave's K-quarter; elements (g, 2+g) feed iterations 2cc, 2cc+1.
    const float4* xrow = (const float4*)x + (rowB + r0) * 64 + wv * 16;
    const bf16x8* wq   = (const bf16x8*)wB + wv * 2048 + l;

    // depth-4 register pipelines (statically indexed under full unroll)
    bf16x8 bfc[4];
    #pragma unroll
    for (int p = 0; p < 4; ++p) bfc[p] = wq[p * 64];
    float4 xq[4];
    #pragma unroll
    for (int p = 0; p < 4; ++p) xq[p] = xrow[p];

    f32x16 accA{}, accB{};

    #pragma unroll
    for (int t = 0; t < 32; ++t) {
        const int cc = t >> 1;
        const float4 f4 = xq[cc & 3];
        const float xv = (t & 1) ? (g ? f4.w : f4.z) : (g ? f4.y : f4.x);
        const bf16x8 bfrag = bfc[t & 3];
        if (t + 4 < 32) bfc[t & 3] = wq[(t + 4) * 64];
        if ((t & 1) && cc + 4 < 16) xq[cc & 3] = xrow[cc + 4];

        const float x2 = xv + xv;
        const float T2 = fmaf(x2, xv, -1.f);
        const float T3 = fmaf(x2, T2, -xv);
        const float T4 = fmaf(x2, T3, -T2);
        const float T5 = fmaf(x2, T4, -T3);
        const float T6 = fmaf(x2, T5, -T4);
        const float T7 = fmaf(x2, T6, -T5);
        unsigned R0 = pkbf_tr(1.f, xv);           // 1 v_perm_b32 each
        unsigned R1 = pkbf_tr(T2, T3);
        unsigned R2 = pkbf_tr(T4, T5);
        unsigned R3 = pkbf_tr(T6, T7);
        // hazard-safe builtin; rounds 6/8/10 HW-verified wiring
        auto r02 = __builtin_amdgcn_permlane32_swap(R0, R2, false, false);
        auto r13 = __builtin_amdgcn_permlane32_swap(R1, R3, false, false);
        union { unsigned u[4]; bf16x8 v; } af;
        af.u[0] = r02[0]; af.u[1] = r13[0];
        af.u[2] = r02[1]; af.u[3] = r13[1];
        if (t & 1)
            accB = __builtin_amdgcn_mfma_f32_32x32x16_bf16(af.v, bfrag, accB, 0, 0, 0);
        else
            accA = __builtin_amdgcn_mfma_f32_32x32x16_bf16(af.v, bfrag, accA, 0, 0, 0);
    }
    const f32x16 acc = accA + accB;

    // ---- partials -> LDS (R4-proven layout), one barrier, 4-way reduce ----
    #pragma unroll
    for (int r = 0; r < 16; ++r) {
        const int rloc = (r & 3) + 8 * (r >> 2) + 4 * g;   // C/D row (HW-verified)
        smem[wv * 1024 + rloc * 32 + r0] = acc[r];
    }
    __syncthreads();

    {
        float* op = out + rowB * 32;
        const int f = tid * 4;                    // 1024 floats / 256 thr
        f32x4 v0 = *(const f32x4*)&smem[f];
        f32x4 v1 = *(const f32x4*)&smem[1024 + f];
        f32x4 v2 = *(const f32x4*)&smem[2048 + f];
        f32x4 v3 = *(const f32x4*)&smem[3072 + f];
        f32x4 s = (v0 + v1) + (v2 + v3);
        *(f32x4*)(op + f) = s;
    }
}

extern "C" void kernel_launch(void* const* d_in, const int* in_sizes, int n_in,
                              void* d_out, int out_size, void* d_ws, size_t ws_size,
                              hipStream_t stream) {
    const float* x = (const float*)d_in[0];   // [65536, 256] fp32
    const float* w = (const float*)d_in[1];   // [32, 256, 8] fp32
    float* out = (float*)d_out;               // [65536, 32] fp32
    short* wB = (short*)d_ws;                 // 128 KB bf16 packed weights

    prep_w_kernel<<<256, 256, 0, stream>>>(w, wB);
    cheb_mm_kernel<<<2048, 256, 0, stream>>>(x, wB, out);
}

// Round 12
// 29.372 us; speedup vs baseline: 1.4192x; 1.4192x over previous
//
#include <hip/hip_runtime.h>
#include <hip/hip_bf16.h>

// out[b,o] = sum_{i,n} T_n(x[b,i]) * w[o,i,n]
// GEMM view: M=B=65536, N=O=32, K=I*8=2048. MFMA v_mfma_f32_32x32x16_bf16.
// Round-12 = Round-10 (best, 29.1 us) + intra-wave CHUNKED stage/compute
// overlap: each wave stages its private 8 KB slice in 4 chunks of 8 kc2;
// chunk c+1's global loads (coalesced, fully-consumed 64B lines) fly while
// chunk c computes. No barriers (wave-private slices), same LDS/layout/math.
// Targets the stage(10us)+compute(13us) convoy that pinned rounds 2-10.

typedef __attribute__((ext_vector_type(8)))  short bf16x8;
typedef __attribute__((ext_vector_type(16))) float f32x16;
typedef __attribute__((ext_vector_type(4)))  float f32x4;

__device__ __forceinline__ short f2b(float f) {     // RN (prep only)
    __hip_bfloat16 h = __float2bfloat16(f);
    short s;
    __builtin_memcpy(&s, &h, sizeof(s));
    return s;
}

// pack {hi16(hi), hi16(lo)} in ONE v_perm_b32 (truncating bf16 pack)
__device__ __forceinline__ unsigned pkbf_tr(float lo, float hi) {
    unsigned a, b;
    __builtin_memcpy(&a, &hi, 4);
    __builtin_memcpy(&b, &lo, 4);
    return __builtin_amdgcn_perm(a, b, 0x07060302u);
}

// Pack w [32][256][8] fp32 -> wB[kc2][lane][jj] bf16 in B-fragment order:
//   o = lane&31, g = lane>>5, i = 2*kc2 + (jj>>2), n = 4*g + (jj&3)
// (HW-verified: rounds 2-11 passed with this layout)
__global__ __launch_bounds__(256) void prep_w_kernel(const float* __restrict__ w,
                                                     short* __restrict__ wB) {
    int idx = blockIdx.x * 256 + threadIdx.x;     // 0..65535
    int kc2 = idx >> 9;
    int l   = (idx >> 3) & 63;
    int jj  = idx & 7;
    int o = l & 31, g = l >> 5;
    int i = 2 * kc2 + (jj >> 2);
    int n = 4 * g + (jj & 3);
    wB[idx] = f2b(w[(o * 256 + i) * 8 + n]);
}

__global__ __launch_bounds__(256, 5) void cheb_mm_kernel(const float* __restrict__ x,
                                                         const short* __restrict__ wB,
                                                         float* __restrict__ out) {
    __shared__ float smem[8192];                  // 32 KB: x tile, then partials
    const int tid = threadIdx.x;
    const int wv  = tid >> 6;                     // K-quarter / column-slice
    const int l   = tid & 63;
    const int g   = l >> 5;                       // i-parity this lane computes
    const int r0  = l & 31;                       // batch row in tile / o column
    const long long rowB = (long long)blockIdx.x * 32;

    const bf16x8* wq = (const bf16x8*)wB + wv * 2048 + l;
    const float4* xg4 = (const float4*)(x + rowB * 256);
    const float* sf = smem;

    // chunk c = this wave's local f2s [8c, 8c+8) = global f4s wv*16+4c..+3.
    // lane stages 2 float4: (row rA, slot sA) and (row rA+16, slot sA):
    // 4 consecutive lanes cover one row's 64B -> 16 fully-consumed lines/instr.
    const int rA = l >> 2;                        // 0..15
    const int sA = l & 3;                         // slot within chunk
    float4 st0, st1;

    auto ISSUE = [&](int c) {                     // global loads, in flight
        const int f4c = wv * 16 + 4 * c + sA;
        st0 = xg4[rA * 64 + f4c];
        st1 = xg4[(rA + 16) * 64 + f4c];
    };
    auto WRITE = [&](int c) {                     // land into proven f2 layout
        const int f4l = 4 * c + sA;
        const int p0 = 2 * f4l, p1 = p0 + 1;
        {
            const int base = rA * 256 + wv * 64, s = rA & 31;
            *(float2*)&smem[base + 2 * (p0 ^ s)] = make_float2(st0.x, st0.y);
            *(float2*)&smem[base + 2 * (p1 ^ s)] = make_float2(st0.z, st0.w);
        }
        {
            const int base = (rA + 16) * 256 + wv * 64, s = (rA + 16) & 31;
            *(float2*)&smem[base + 2 * (p0 ^ s)] = make_float2(st1.x, st1.y);
            *(float2*)&smem[base + 2 * (p1 ^ s)] = make_float2(st1.z, st1.w);
        }
    };

    ISSUE(0);
    // B prefetch flies under the x wait (L2-resident)
    bf16x8 bfc[4];
    #pragma unroll
    for (int p = 0; p < 4; ++p) bfc[p] = wq[p * 64];

    f32x16 accA{}, accB{};
    const int base0 = r0 * 256 + wv * 64 + g + (r0 << 1);   // R10 addressing

    WRITE(0);
    ISSUE(1);

    #pragma unroll
    for (int c = 0; c < 4; ++c) {
        // ---- compute chunk c: t = 8c..8c+7 (R10-proven body) ----
        float xc[4];
        #pragma unroll
        for (int j = 0; j < 4; ++j) xc[j] = sf[base0 ^ ((8 * c + j) << 1)];
        #pragma unroll
        for (int j = 0; j < 8; ++j) {
            const int t = 8 * c + j;
            const bf16x8 bfrag = bfc[t & 3];
            const float  xv    = xc[j & 3];
            if (t + 4 < 32) bfc[t & 3] = wq[(t + 4) * 64];
            if (j + 4 < 8)  xc[j & 3]  = sf[base0 ^ ((t + 4) << 1)];

            const float x2 = xv + xv;
            const float T2 = fmaf(x2, xv, -1.f);
            const float T3 = fmaf(x2, T2, -xv);
            const float T4 = fmaf(x2, T3, -T2);
            const float T5 = fmaf(x2, T4, -T3);
            const float T6 = fmaf(x2, T5, -T4);
            const float T7 = fmaf(x2, T6, -T5);
            unsigned R0 = pkbf_tr(1.f, xv);       // 1 v_perm_b32 each
            unsigned R1 = pkbf_tr(T2, T3);
            unsigned R2 = pkbf_tr(T4, T5);
            unsigned R3 = pkbf_tr(T6, T7);
            auto r02 = __builtin_amdgcn_permlane32_swap(R0, R2, false, false);
            auto r13 = __builtin_amdgcn_permlane32_swap(R1, R3, false, false);
            union { unsigned u[4]; bf16x8 v; } af;
            af.u[0] = r02[0]; af.u[1] = r13[0];
            af.u[2] = r02[1]; af.u[3] = r13[1];
            if (t & 1)
                accB = __builtin_amdgcn_mfma_f32_32x32x16_bf16(af.v, bfrag, accB, 0, 0, 0);
            else
                accA = __builtin_amdgcn_mfma_f32_32x32x16_bf16(af.v, bfrag, accA, 0, 0, 0);
        }
        // ---- land chunk c+1 (loads have been in flight during compute) ----
        if (c < 3) {
            WRITE(c + 1);
            if (c < 2) ISSUE(c + 2);
        }
    }
    const f32x16 acc = accA + accB;

    // ---- partials into this wave's own (dead) slice: no barrier needed ----
    #pragma unroll
    for (int r = 0; r < 16; ++r) {
        const int rloc = (r & 3) + 8 * (r >> 2) + 4 * g;   // C/D row (HW-verified)
        smem[rloc * 256 + wv * 64 + r0] = acc[r];
    }
    __syncthreads();                              // the block's ONLY barrier

    // ---- cross-wave reduce + coalesced f32x4 store of out[32][32] ----
    {
        float* op = out + rowB * 32;
        const int f   = tid * 4;                  // 1024 floats / 256 thr
        const int row = f >> 5;
        const int c2  = f & 31;
        const int b   = row * 256 + c2;
        f32x4 v0 = *(const f32x4*)&smem[b];
        f32x4 v1 = *(const f32x4*)&smem[b + 64];
        f32x4 v2 = *(const f32x4*)&smem[b + 128];
        f32x4 v3 = *(const f32x4*)&smem[b + 192];
        f32x4 s = (v0 + v1) + (v2 + v3);
        *(f32x4*)(op + f) = s;
    }
}

extern "C" void kernel_launch(void* const* d_in, const int* in_sizes, int n_in,
                              void* d_out, int out_size, void* d_ws, size_t ws_size,
                              hipStream_t stream) {
    const float* x = (const float*)d_in[0];   // [65536, 256] fp32
    const float* w = (const float*)d_in[1];   // [32, 256, 8] fp32
    float* out = (float*)d_out;               // [65536, 32] fp32
    short* wB = (short*)d_ws;                 // 128 KB bf16 packed weights

    prep_w_kernel<<<256, 256, 0, stream>>>(w, wB);
    cheb_mm_kernel<<<2048, 256, 0, stream>>>(x, wB, out);
}